// Round 5
// baseline (181.205 us; speedup 1.0000x reference)
//
#include <hip/hip_runtime.h>
#include <cstdint>
#include <cstddef>

// Problem constants
#define HW 512
#define NPIX (HW * HW)           // 262144 pixels per image
#define NIMG 16
#define NII 32                   // (input j, image n) pairs: ii = j*16 + n
#define CHUNKS 64
#define CHUNK_PIX 4096
#define IN_ELEMS (NIMG * NPIX)   // 4194304 per input
#define WPI 4096                 // u64 words per ii (512 rows * 8)

typedef unsigned long long u64;

// Workspace layout (bytes)
#define WS_PARTA 0u                      // 32*64 entries * 4 doubles = 65536
#define WS_ZM    65536u                  // 32 u64
#define WS_MSEL  98304u                  // selected marker bitmaps (1 MB)
#define WS_KSEL  (WS_MSEL + 1048576u)    // selected mask bitmaps (1 MB)
#define WS_ROUT  (WS_KSEL + 1048576u)    // reconstruction result (1 MB)

// f64 sigmoid rounded to f32 — EXACT round-1 numerics. Used ONLY in find_cut.
__device__ __forceinline__ float sigmoid_f32(float x) {
    return (float)(1.0 / (1.0 + exp(-(double)x)));
}

// Fast f64 sigmoid for STATS ONLY (proven R5/R6, absmax 0.0).
__device__ __forceinline__ float sigmoid_fast(float xf) {
    double x = (double)xf;
    double y = x * -1.4426950408889634074;     // log2(e)
    if (y > 1000.0)  return 0.0f;
    if (y < -1000.0) return 1.0f;
    double n = __builtin_rint(y);
    double t = (y - n) * 0.69314718055994530942;
    double p = 2.5052108385441718775e-8;
    p = __builtin_fma(p, t, 2.7557319223985890653e-7);
    p = __builtin_fma(p, t, 2.7557319223985892511e-6);
    p = __builtin_fma(p, t, 2.4801587301587301566e-5);
    p = __builtin_fma(p, t, 1.9841269841269841253e-4);
    p = __builtin_fma(p, t, 1.3888888888888889419e-3);
    p = __builtin_fma(p, t, 8.3333333333333332177e-3);
    p = __builtin_fma(p, t, 4.1666666666666664354e-2);
    p = __builtin_fma(p, t, 1.6666666666666665741e-1);
    p = __builtin_fma(p, t, 5.0e-1);
    p = __builtin_fma(p, t, 1.0);
    p = __builtin_fma(p, t, 1.0);
    long long bits = ((long long)n + 1023ll) << 52;
    double e = p * __longlong_as_double(bits);     // exp(-x)
    double d = 1.0 + e;
    if (y > 100.0 || y < -100.0)
        return (float)(1.0 / d);
    double r = (double)__builtin_amdgcn_rcpf((float)d);
    r = r * (2.0 - d * r);
    r = r * (2.0 - d * r);
    return (float)r;
}

// ---------------------------------------------------------------------------
// k1: single input pass — passthrough copy + f64 partials {sum,sumsq,cnt,max}.
// (byte-identical to the best-measured R0 configuration)
__global__ void k1_copy_stats(const float* __restrict__ A, const float* __restrict__ B,
                              float* __restrict__ out, double* __restrict__ partA) {
    int b = blockIdx.x;            // 0..2047
    int ii = b >> 6, chunk = b & 63;
    int j = ii >> 4, n = ii & 15;
    const float* src = (j == 0 ? A : B) + (size_t)n * NPIX + (size_t)chunk * CHUNK_PIX;
    float* dst = out + (size_t)j * IN_ELEMS + (size_t)n * NPIX + (size_t)chunk * CHUNK_PIX;

    double s = 0.0, sq = 0.0, cc = 0.0;
    float mx = -__builtin_inff();
#pragma unroll
    for (int p = 0; p < 4; ++p) {
        float4 v = *(const float4*)(src + p * 1024 + threadIdx.x * 4);
        *(float4*)(dst + p * 1024 + threadIdx.x * 4) = v;
        float xs[4] = {v.x, v.y, v.z, v.w};
#pragma unroll
        for (int q = 0; q < 4; ++q) {
            float img = sigmoid_fast(xs[q]);
            mx = fmaxf(mx, xs[q]);
            if (img > 0.0f) { double d = (double)img; s += d; sq += d * d; cc += 1.0; }
        }
    }
    __shared__ double sm[256], sv[256], sc[256];
    __shared__ float smx[256];
    sm[threadIdx.x] = s; sv[threadIdx.x] = sq; sc[threadIdx.x] = cc; smx[threadIdx.x] = mx;
    __syncthreads();
    for (int off = 128; off > 0; off >>= 1) {
        if (threadIdx.x < off) {
            sm[threadIdx.x] += sm[threadIdx.x + off];
            sv[threadIdx.x] += sv[threadIdx.x + off];
            sc[threadIdx.x] += sc[threadIdx.x + off];
            smx[threadIdx.x] = fmaxf(smx[threadIdx.x], smx[threadIdx.x + off]);
        }
        __syncthreads();
    }
    if (threadIdx.x == 0) {
        double* p = partA + (size_t)(ii * 64 + chunk) * 4;
        p[0] = sm[0]; p[1] = sv[0]; p[2] = sc[0]; p[3] = (double)smx[0];
    }
}

// ---------------------------------------------------------------------------
// cutoff bisection over ordered-f32 key space with the exact libm sigmoid
// (proven bit-exact R2-R6).
__device__ __forceinline__ float key_to_f32(unsigned k) {
    unsigned b = (k & 0x80000000u) ? (k ^ 0x80000000u) : ~k;
    return __uint_as_float(b);
}
__device__ float find_cut(double T) {
    if (!(1.0 > T)) return __uint_as_float(0x7F800000u);
    unsigned lo = 0x007FFFFFu;   // key(-inf)
    unsigned hi = 0xFF800000u;   // key(+inf)
    while (lo < hi) {
        unsigned mid = lo + ((hi - lo) >> 1);
        float x = key_to_f32(mid);
        float s32 = sigmoid_f32(x);
        if ((double)s32 > T) hi = mid; else lo = mid + 1;
    }
    return key_to_f32(lo);
}

// ---------------------------------------------------------------------------
// k2: per-block redundant cutoff computation + selected marker/mask bitmaps
// via ballots + zm. (unchanged — proven)
__global__ void k2_bits(const float* __restrict__ A, const float* __restrict__ B,
                        const double* __restrict__ partA,
                        u64* __restrict__ msel, u64* __restrict__ ksel,
                        u64* __restrict__ zm) {
    int b = blockIdx.x, ii = b >> 6, chunk = b & 63;
    int j = ii >> 4, n = ii & 15;
    const float* src = (j == 0 ? A : B) + (size_t)n * NPIX;
    int t = threadIdx.x, lane = t & 63, w = t >> 6;

    __shared__ double shst[4];     // mean, sd, cnt, max
    __shared__ float cs[4];
    __shared__ float cut2[2];

    if (t < 64) {
        const double* p = partA + (size_t)(ii * 64 + t) * 4;
        double s = p[0], sq = p[1], c = p[2], mx = p[3];
#pragma unroll
        for (int off = 32; off > 0; off >>= 1) {
            s  += __shfl_down(s,  (unsigned)off, 64);
            sq += __shfl_down(sq, (unsigned)off, 64);
            c  += __shfl_down(c,  (unsigned)off, 64);
            mx  = fmax(mx, __shfl_down(mx, (unsigned)off, 64));
        }
        if (t == 0) {
            double mean = 0.0, sd = 0.0;
            if (c > 0.0) {
                mean = s / c;
                double var = sq / c - mean * mean;
                if (var < 0.0) var = 0.0;
                sd = sqrt(var);
            }
            shst[0] = mean; shst[1] = sd; shst[2] = c; shst[3] = mx;
        }
    }
    __syncthreads();
    if (t < 4) {
        double mean = shst[0], sd = shst[1];
        double fac = (ii < 16) ? 2.0 : 4.0;
        double T = (t == 0) ? mean + fac * sd
                 : (t == 1) ? mean + 0.5 * fac * sd
                 : (t == 2) ? mean + 0.5 * sd
                 :            mean + 0.25 * sd;
        cs[t] = find_cut(T);
    }
    __syncthreads();
    if (t == 0) {
        float mxf = (float)shst[3];
        cut2[0] = (mxf >= cs[0]) ? cs[0] : cs[1];   // marker (empty-fallback via max)
        cut2[1] = (mxf >= cs[2]) ? cs[2] : cs[3];   // mask
        if (chunk == 0) zm[ii] = (shst[2] > 0.0) ? ~0ull : 0ull;
    }
    __syncthreads();
    float cM = cut2[0], cK = cut2[1];

#pragma unroll 4
    for (int i = 0; i < 16; ++i) {
        float x = src[chunk * CHUNK_PIX + i * 256 + t];
        u64 bM = __ballot(x >= cM);
        u64 bK = __ballot(x >= cK);
        if (lane == 0) {
            size_t g = (size_t)ii * WPI + (size_t)chunk * 64 + i * 4 + w;
            msel[g] = bM; ksel[g] = bK;
        }
    }
}

// ---------------------------------------------------------------------------
// Masked horizontal fill of a 512-bit line to FIXPOINT in O(1) (proven R2-R6).
__device__ __forceinline__ void hfill8(u64* x, const u64* k) {
    u64 c = 0;
#pragma unroll
    for (int w = 0; w < 8; ++w) {
        u64 a = k[w], g = x[w];
        u64 t1 = a + g;  u64 c1 = (u64)(t1 < a);
        u64 t2 = t1 + c; u64 c2 = (u64)(t2 < t1);
        c = c1 | c2;
        x[w] = (~t2 | g) & a;
    }
    c = 0;
#pragma unroll
    for (int w = 7; w >= 0; --w) {
        u64 a = __brevll(k[w]), g = __brevll(x[w]);
        u64 t1 = a + g;  u64 c1 = (u64)(t1 < a);
        u64 t2 = t1 + c; u64 c2 = (u64)(t2 < t1);
        c = c1 | c2;
        x[w] = __brevll((~t2 | g) & a);
    }
}

// ---------------------------------------------------------------------------
// 512x512 bit-transpose helper. Layout S/D[w*512 + row] (w = 64-col word idx).
// 64x64 blocks; one word per lane; 6-stage butterfly, verified against the
// canonical serial algorithm under the LSB=column convention:
//   t = ((A[k]>>j) ^ A[k|j]) & m;  A[k] ^= t<<j;  A[k|j] ^= t;
// Block (I,J) -> (J,I): D[I*512 + J*64 + L] = xp64(S[J*512 + I*64 + L]).
// Involution by construction (applying it twice is identity).
#define XSTAGE(jc, mc) {                                     \
    u64 p  = __shfl_xor(x, jc, 64);                          \
    u64 lo = (L & jc) ? p : x;   /* word with j-bit 0 */     \
    u64 hi = (L & jc) ? x : p;   /* word with j-bit 1 */     \
    u64 tt = ((lo >> jc) ^ hi) & mc;                         \
    x ^= (L & jc) ? tt : (tt << jc); }

__device__ __forceinline__ void xpose512(const u64* __restrict__ S,
                                         u64* __restrict__ D,
                                         int L, int I, int J0) {
#pragma unroll
    for (int jj = 0; jj < 4; ++jj) {
        int J = J0 + jj;
        u64 x = S[J * 512 + I * 64 + L];
        XSTAGE(32, 0x00000000FFFFFFFFull)
        XSTAGE(16, 0x0000FFFF0000FFFFull)
        XSTAGE(8,  0x00FF00FF00FF00FFull)
        XSTAGE(4,  0x0F0F0F0F0F0F0F0Full)
        XSTAGE(2,  0x3333333333333333ull)
        XSTAGE(1,  0x5555555555555555ull)
        D[I * 512 + J * 64 + L] = x;
    }
}

// ---------------------------------------------------------------------------
// k3: morphological reconstruction via alternating H/V directional fills.
// 32 blocks x 1024 threads (16 waves). State in LDS row-rep Rb[w*512+row];
// per cycle: transpose Rb->Tb (full 512x512 bit transpose, lane butterfly),
// hfill8 every transposed row (= every COLUMN, O(1) vertical fill, mask K^T),
// transpose back, hfill8 every row. Fully barrier-ordered — no racing reads.
// Exit when a complete cycle gains no bit anywhere: state stable under both
// H-fill and V-fill => stable under 4-neighbor dilation => exact fixpoint
// (>= marker, <= mask, built from monotone propagation only). Convergence is
// O(#bends in cluster geodesics) cycles — ~10 for subcritical randn clusters
// — instead of O(rows) LDS sweeps.
__global__ __launch_bounds__(1024) void k3_hv(const u64* __restrict__ msel,
                                              const u64* __restrict__ ksel,
                                              u64* __restrict__ rout) {
    __shared__ u64 Rb[8 * HW];   // 32 KB row-rep
    __shared__ u64 Tb[8 * HW];   // 32 KB col-rep (transpose scratch)
    int ii = blockIdx.x, t = threadIdx.x;
    int L = t & 63, W = t >> 6;         // lane, wave 0..15
    int I = W >> 1, J0 = (W & 1) * 4;   // transpose work split: 4 blocks/lane
    const u64* M = msel + (size_t)ii * WPI;
    const u64* K = ksel + (size_t)ii * WPI;

    u64 k8[8], kT8[8], r8[8];
    if (t < HW) {
#pragma unroll
        for (int w = 0; w < 8; ++w) {
            k8[w] = K[(size_t)t * 8 + w];
            r8[w] = M[(size_t)t * 8 + w] & k8[w];   // marker ⊆ mask
        }
        hfill8(r8, k8);                              // initial horizontal fixpoint
#pragma unroll
        for (int w = 0; w < 8; ++w) Rb[w * HW + t] = k8[w];  // stage K for K^T
    }
    __syncthreads();
    xpose512(Rb, Tb, L, I, J0);          // Tb = K^T
    __syncthreads();
    if (t < HW) {
#pragma unroll
        for (int w = 0; w < 8; ++w) kT8[w] = Tb[w * HW + t];
#pragma unroll
        for (int w = 0; w < 8; ++w) Rb[w * HW + t] = r8[w]; // Rb = state
    }
    __syncthreads();

    for (int cyc = 0; cyc < 200; ++cyc) {
        // ---- vertical pass: transpose, fill columns, transpose back
        xpose512(Rb, Tb, L, I, J0);
        __syncthreads();
        u64 d = 0;
        if (t < HW) {
            u64 x8[8], o8[8];
#pragma unroll
            for (int w = 0; w < 8; ++w) { x8[w] = Tb[w * HW + t]; o8[w] = x8[w]; }
            hfill8(x8, kT8);
            u64 dd = 0;
#pragma unroll
            for (int w = 0; w < 8; ++w) dd |= x8[w] ^ o8[w];
            if (dd) {
#pragma unroll
                for (int w = 0; w < 8; ++w) Tb[w * HW + t] = x8[w];
            }
            d |= dd;
        }
        __syncthreads();
        xpose512(Tb, Rb, L, I, J0);
        __syncthreads();
        // ---- horizontal pass on rows
        if (t < HW) {
            u64 x8[8], o8[8];
#pragma unroll
            for (int w = 0; w < 8; ++w) { x8[w] = Rb[w * HW + t]; o8[w] = x8[w]; }
            hfill8(x8, k8);
            u64 dd = 0;
#pragma unroll
            for (int w = 0; w < 8; ++w) dd |= x8[w] ^ o8[w];
            if (dd) {
#pragma unroll
                for (int w = 0; w < 8; ++w) Rb[w * HW + t] = x8[w];
            }
            d |= dd;
        }
        if (!__syncthreads_or(d != 0ull ? 1 : 0)) break;   // clean cycle = fixpoint
    }

    // word-interleaved output rout[ii*WPI + w*HW + row] (same format as before;
    // thread t's row was last written by thread t itself — own writes visible)
    if (t < HW) {
#pragma unroll
        for (int w = 0; w < 8; ++w)
            rout[(size_t)ii * WPI + (size_t)w * HW + t] = Rb[w * HW + t];
    }
}

// ---------------------------------------------------------------------------
// k4: fused output = OR of the two reconstructions (masked by cnt>0), f32 0/1.
// (unchanged — proven; rout word-interleaved idx = w*512 + row)
__global__ void k4_fuse(const u64* __restrict__ rout,
                        const u64* __restrict__ zm,
                        float* __restrict__ out) {
    size_t gid = (size_t)blockIdx.x * blockDim.x + threadIdx.x;
    size_t p = gid * 4;
    int n = (int)(p >> 18);
    int e = (int)(p & (NPIX - 1));
    size_t gw = (size_t)(((e >> 6) & 7) * HW + (e >> 9));
    u64 w = (rout[(size_t)n * WPI + gw] & zm[n])
          | (rout[(size_t)(16 + n) * WPI + gw] & zm[16 + n]);
    int sh = e & 63;
    float4 v;
    v.x = ((w >> sh) & 1ull)       ? 1.0f : 0.0f;
    v.y = ((w >> (sh + 1)) & 1ull) ? 1.0f : 0.0f;
    v.z = ((w >> (sh + 2)) & 1ull) ? 1.0f : 0.0f;
    v.w = ((w >> (sh + 3)) & 1ull) ? 1.0f : 0.0f;
    *(float4*)(out + 2 * (size_t)IN_ELEMS + p) = v;
}

extern "C" void kernel_launch(void* const* d_in, const int* in_sizes, int n_in,
                              void* d_out, int out_size, void* d_ws, size_t ws_size,
                              hipStream_t stream) {
    const float* A = (const float*)d_in[0];
    const float* B = (const float*)d_in[1];
    float* out = (float*)d_out;
    char* ws = (char*)d_ws;

    double* partA = (double*)(ws + WS_PARTA);
    u64*    zm    = (u64*)(ws + WS_ZM);
    u64*    msel  = (u64*)(ws + WS_MSEL);
    u64*    ksel  = (u64*)(ws + WS_KSEL);
    u64*    rout  = (u64*)(ws + WS_ROUT);

    k1_copy_stats<<<NII * CHUNKS, 256, 0, stream>>>(A, B, out, partA);
    k2_bits<<<NII * CHUNKS, 256, 0, stream>>>(A, B, partA, msel, ksel, zm);
    k3_hv<<<NII, 1024, 0, stream>>>(msel, ksel, rout);
    k4_fuse<<<4096, 256, 0, stream>>>(rout, zm, out);
}

// Round 6
// 179.505 us; speedup vs baseline: 1.0095x; 1.0095x over previous
//
#include <hip/hip_runtime.h>
#include <cstdint>
#include <cstddef>

// Problem constants
#define HW 512
#define NPIX (HW * HW)           // 262144 pixels per image
#define NIMG 16
#define NII 32                   // (input j, image n) pairs: ii = j*16 + n
#define CHUNKS 64
#define CHUNK_PIX 4096
#define IN_ELEMS (NIMG * NPIX)   // 4194304 per input
#define WPI 4096                 // u64 words per ii (512 rows * 8)

typedef unsigned long long u64;

// Workspace layout (bytes)
#define WS_PARTA 0u                      // 32*64 entries * 4 doubles = 65536
#define WS_ZM    65536u                  // 32 u64
#define WS_MSEL  98304u                  // selected marker bitmaps (1 MB)
#define WS_KSEL  (WS_MSEL + 1048576u)    // selected mask bitmaps (1 MB)
#define WS_ROUT  (WS_KSEL + 1048576u)    // reconstruction result (1 MB)

// f64 sigmoid rounded to f32 — EXACT round-1 numerics. Used ONLY in find_cut.
__device__ __forceinline__ float sigmoid_f32(float x) {
    return (float)(1.0 / (1.0 + exp(-(double)x)));
}

// Fast f64 sigmoid for STATS ONLY (proven, absmax 0.0).
__device__ __forceinline__ float sigmoid_fast(float xf) {
    double x = (double)xf;
    double y = x * -1.4426950408889634074;     // log2(e)
    if (y > 1000.0)  return 0.0f;
    if (y < -1000.0) return 1.0f;
    double n = __builtin_rint(y);
    double t = (y - n) * 0.69314718055994530942;
    double p = 2.5052108385441718775e-8;
    p = __builtin_fma(p, t, 2.7557319223985890653e-7);
    p = __builtin_fma(p, t, 2.7557319223985892511e-6);
    p = __builtin_fma(p, t, 2.4801587301587301566e-5);
    p = __builtin_fma(p, t, 1.9841269841269841253e-4);
    p = __builtin_fma(p, t, 1.3888888888888889419e-3);
    p = __builtin_fma(p, t, 8.3333333333333332177e-3);
    p = __builtin_fma(p, t, 4.1666666666666664354e-2);
    p = __builtin_fma(p, t, 1.6666666666666665741e-1);
    p = __builtin_fma(p, t, 5.0e-1);
    p = __builtin_fma(p, t, 1.0);
    p = __builtin_fma(p, t, 1.0);
    long long bits = ((long long)n + 1023ll) << 52;
    double e = p * __longlong_as_double(bits);     // exp(-x)
    double d = 1.0 + e;
    if (y > 100.0 || y < -100.0)
        return (float)(1.0 / d);
    double r = (double)__builtin_amdgcn_rcpf((float)d);
    r = r * (2.0 - d * r);
    r = r * (2.0 - d * r);
    return (float)r;
}

// ---------------------------------------------------------------------------
// k1: single input pass — passthrough copy + f64 partials {sum,sumsq,cnt,max}.
// (byte-identical to the best-measured R0 configuration)
__global__ void k1_copy_stats(const float* __restrict__ A, const float* __restrict__ B,
                              float* __restrict__ out, double* __restrict__ partA) {
    int b = blockIdx.x;            // 0..2047
    int ii = b >> 6, chunk = b & 63;
    int j = ii >> 4, n = ii & 15;
    const float* src = (j == 0 ? A : B) + (size_t)n * NPIX + (size_t)chunk * CHUNK_PIX;
    float* dst = out + (size_t)j * IN_ELEMS + (size_t)n * NPIX + (size_t)chunk * CHUNK_PIX;

    double s = 0.0, sq = 0.0, cc = 0.0;
    float mx = -__builtin_inff();
#pragma unroll
    for (int p = 0; p < 4; ++p) {
        float4 v = *(const float4*)(src + p * 1024 + threadIdx.x * 4);
        *(float4*)(dst + p * 1024 + threadIdx.x * 4) = v;
        float xs[4] = {v.x, v.y, v.z, v.w};
#pragma unroll
        for (int q = 0; q < 4; ++q) {
            float img = sigmoid_fast(xs[q]);
            mx = fmaxf(mx, xs[q]);
            if (img > 0.0f) { double d = (double)img; s += d; sq += d * d; cc += 1.0; }
        }
    }
    __shared__ double sm[256], sv[256], sc[256];
    __shared__ float smx[256];
    sm[threadIdx.x] = s; sv[threadIdx.x] = sq; sc[threadIdx.x] = cc; smx[threadIdx.x] = mx;
    __syncthreads();
    for (int off = 128; off > 0; off >>= 1) {
        if (threadIdx.x < off) {
            sm[threadIdx.x] += sm[threadIdx.x + off];
            sv[threadIdx.x] += sv[threadIdx.x + off];
            sc[threadIdx.x] += sc[threadIdx.x + off];
            smx[threadIdx.x] = fmaxf(smx[threadIdx.x], smx[threadIdx.x + off]);
        }
        __syncthreads();
    }
    if (threadIdx.x == 0) {
        double* p = partA + (size_t)(ii * 64 + chunk) * 4;
        p[0] = sm[0]; p[1] = sv[0]; p[2] = sc[0]; p[3] = (double)smx[0];
    }
}

// ---------------------------------------------------------------------------
// cutoff bisection over ordered-f32 key space with the exact libm sigmoid
// (proven bit-exact).
__device__ __forceinline__ float key_to_f32(unsigned k) {
    unsigned b = (k & 0x80000000u) ? (k ^ 0x80000000u) : ~k;
    return __uint_as_float(b);
}
__device__ float find_cut(double T) {
    if (!(1.0 > T)) return __uint_as_float(0x7F800000u);
    unsigned lo = 0x007FFFFFu;   // key(-inf)
    unsigned hi = 0xFF800000u;   // key(+inf)
    while (lo < hi) {
        unsigned mid = lo + ((hi - lo) >> 1);
        float x = key_to_f32(mid);
        float s32 = sigmoid_f32(x);
        if ((double)s32 > T) hi = mid; else lo = mid + 1;
    }
    return key_to_f32(lo);
}

// ---------------------------------------------------------------------------
// k2: per-block redundant cutoff computation + selected marker/mask bitmaps
// via ballots + zm. (unchanged — proven)
__global__ void k2_bits(const float* __restrict__ A, const float* __restrict__ B,
                        const double* __restrict__ partA,
                        u64* __restrict__ msel, u64* __restrict__ ksel,
                        u64* __restrict__ zm) {
    int b = blockIdx.x, ii = b >> 6, chunk = b & 63;
    int j = ii >> 4, n = ii & 15;
    const float* src = (j == 0 ? A : B) + (size_t)n * NPIX;
    int t = threadIdx.x, lane = t & 63, w = t >> 6;

    __shared__ double shst[4];     // mean, sd, cnt, max
    __shared__ float cs[4];
    __shared__ float cut2[2];

    if (t < 64) {
        const double* p = partA + (size_t)(ii * 64 + t) * 4;
        double s = p[0], sq = p[1], c = p[2], mx = p[3];
#pragma unroll
        for (int off = 32; off > 0; off >>= 1) {
            s  += __shfl_down(s,  (unsigned)off, 64);
            sq += __shfl_down(sq, (unsigned)off, 64);
            c  += __shfl_down(c,  (unsigned)off, 64);
            mx  = fmax(mx, __shfl_down(mx, (unsigned)off, 64));
        }
        if (t == 0) {
            double mean = 0.0, sd = 0.0;
            if (c > 0.0) {
                mean = s / c;
                double var = sq / c - mean * mean;
                if (var < 0.0) var = 0.0;
                sd = sqrt(var);
            }
            shst[0] = mean; shst[1] = sd; shst[2] = c; shst[3] = mx;
        }
    }
    __syncthreads();
    if (t < 4) {
        double mean = shst[0], sd = shst[1];
        double fac = (ii < 16) ? 2.0 : 4.0;
        double T = (t == 0) ? mean + fac * sd
                 : (t == 1) ? mean + 0.5 * fac * sd
                 : (t == 2) ? mean + 0.5 * sd
                 :            mean + 0.25 * sd;
        cs[t] = find_cut(T);
    }
    __syncthreads();
    if (t == 0) {
        float mxf = (float)shst[3];
        cut2[0] = (mxf >= cs[0]) ? cs[0] : cs[1];   // marker (empty-fallback via max)
        cut2[1] = (mxf >= cs[2]) ? cs[2] : cs[3];   // mask
        if (chunk == 0) zm[ii] = (shst[2] > 0.0) ? ~0ull : 0ull;
    }
    __syncthreads();
    float cM = cut2[0], cK = cut2[1];

#pragma unroll 4
    for (int i = 0; i < 16; ++i) {
        float x = src[chunk * CHUNK_PIX + i * 256 + t];
        u64 bM = __ballot(x >= cM);
        u64 bK = __ballot(x >= cK);
        if (lane == 0) {
            size_t g = (size_t)ii * WPI + (size_t)chunk * 64 + i * 4 + w;
            msel[g] = bM; ksel[g] = bK;
        }
    }
}

// ---------------------------------------------------------------------------
// Masked horizontal fill of a 512-bit line to FIXPOINT in O(1) (proven).
__device__ __forceinline__ void hfill8(u64* x, const u64* k) {
    u64 c = 0;
#pragma unroll
    for (int w = 0; w < 8; ++w) {
        u64 a = k[w], g = x[w];
        u64 t1 = a + g;  u64 c1 = (u64)(t1 < a);
        u64 t2 = t1 + c; u64 c2 = (u64)(t2 < t1);
        c = c1 | c2;
        x[w] = (~t2 | g) & a;
    }
    c = 0;
#pragma unroll
    for (int w = 7; w >= 0; --w) {
        u64 a = __brevll(k[w]), g = __brevll(x[w]);
        u64 t1 = a + g;  u64 c1 = (u64)(t1 < a);
        u64 t2 = t1 + c; u64 c2 = (u64)(t2 < t1);
        c = c1 | c2;
        x[w] = __brevll((~t2 | g) & a);
    }
}

// ---------------------------------------------------------------------------
// Masked cross-lane shfl with out-of-range zeroing (shfl first, then select —
// keeps the convergent op unconditional).
__device__ __forceinline__ u64 shu64(u64 x, int d, int lane) {
    u64 y = __shfl_up(x, (unsigned)d, 64);
    return (lane >= d) ? y : 0ull;
}
__device__ __forceinline__ u64 shd64(u64 x, int d, int lane) {
    u64 y = __shfl_down(x, (unsigned)d, 64);
    return (lane + d <= 63) ? y : 0ull;
}

// ---------------------------------------------------------------------------
// Stripe stabilizer: iterate {vertical masked-run fill via shfl doubling
// (reach <=8 rows each direction — vertical runs at ~33% density are short),
// then hfill8 on rows that gained} until the wave's 64-row stripe is a local
// fixpoint. Segmented-OR doubling: val_d[i] = OR of r[j] within k-run of
// length <=d ending at i; ok_d = run-AND of k, doubled alongside. Reach-1 is
// contained in reach-8, so "V-pass gained nothing on an H-stable state" =>
// stripe is 4-neighbor stationary. redo flags the (never-expected) cap exit
// so the outer loop cannot falsely certify a fixpoint.
__device__ __forceinline__ u64 vstab(u64 (&r)[8], const u64 (&k)[8], int lane, bool& redo) {
    u64 total = 0;
    bool more;
    int it = 0;
    do {
        u64 vdiff = 0;
#pragma unroll
        for (int w = 0; w < 8; ++w) {
            u64 o = k[w];
            // downward flow (sources at smaller lane / upper rows)
            u64 v = r[w], ok = o, sv, so;
            v |= shu64(v, 1, lane) & ok;                                        // <=1
            sv = shu64(v, 1, lane); so = shu64(ok, 1, lane); v |= sv & ok; ok &= so; // <=2
            sv = shu64(v, 2, lane); so = shu64(ok, 2, lane); v |= sv & ok; ok &= so; // <=4
            v |= shu64(v, 4, lane) & ok;                                        // <=8
            u64 dn = v;
            // upward flow (sources at larger lane / lower rows)
            v = r[w]; ok = o;
            v |= shd64(v, 1, lane) & ok;
            sv = shd64(v, 1, lane); so = shd64(ok, 1, lane); v |= sv & ok; ok &= so;
            sv = shd64(v, 2, lane); so = shd64(ok, 2, lane); v |= sv & ok; ok &= so;
            v |= shd64(v, 4, lane) & ok;
            u64 nw = dn | v;               // both include r itself
            vdiff |= nw ^ r[w];
            r[w] = nw;
        }
        if (vdiff) hfill8(r, k);           // restore per-row H-fixpoint
        total |= vdiff;
        more = (__any((int)(vdiff != 0ull)) != 0);
    } while (more && ++it < 32);
    redo = more;
    return total;
}

// ---------------------------------------------------------------------------
// k3: morphological reconstruction — register-stripe flood.
// 32 blocks x 512 threads. Wave wv owns rows 64wv..64wv+63, ONE ROW PER LANE
// in registers (r[8], k[8]). Vertical propagation inside a stripe runs at
// shfl speed (vstab); stripes couple ONLY through their 2 boundary rows,
// published to 1 KB of LDS and read barrier-ordered (no racing reads at all).
// Per round: absorb neighbor boundary rows (lanes 0/63), hfill, stabilize the
// stripe, republish, __syncthreads_or window. Exit on a clean round: every
// stripe internally stationary (vstab fixpoint, reach-1 included) AND no
// boundary absorption possible => exact global fixpoint. Monotone throughout.
__global__ __launch_bounds__(512) void k3_flood(const u64* __restrict__ msel,
                                                const u64* __restrict__ ksel,
                                                u64* __restrict__ rout) {
    int ii = blockIdx.x, t = threadIdx.x;
    int lane = t & 63, wv = t >> 6;        // stripe index 0..7
    __shared__ u64 Btop[8][8];             // published top row of each stripe
    __shared__ u64 Bbot[8][8];             // published bottom row
    const u64* M = msel + (size_t)ii * WPI;
    const u64* K = ksel + (size_t)ii * WPI;

    u64 r[8], k[8];
#pragma unroll
    for (int w = 0; w < 8; ++w) {
        k[w] = K[(size_t)t * 8 + w];
        r[w] = M[(size_t)t * 8 + w] & k[w];   // marker ⊆ mask (Tm >= Tk always)
    }
    hfill8(r, k);
    bool redo;
    vstab(r, k, lane, redo);                   // stripe-local fixpoint
    if (lane == 0) {
#pragma unroll
        for (int w = 0; w < 8; ++w) Btop[wv][w] = r[w];
    }
    if (lane == 63) {
#pragma unroll
        for (int w = 0; w < 8; ++w) Bbot[wv][w] = r[w];
    }
    __syncthreads();

    for (int round = 0; round < 256; ++round) {
        u64 g = 0;
        if (lane == 0 && wv > 0) {             // absorb row 64wv-1 from stripe above
#pragma unroll
            for (int w = 0; w < 8; ++w) {
                u64 a = Bbot[wv - 1][w] & k[w] & ~r[w];
                r[w] |= a; g |= a;
            }
        } else if (lane == 63 && wv < 7) {     // absorb row 64wv+64 from stripe below
#pragma unroll
            for (int w = 0; w < 8; ++w) {
                u64 a = Btop[wv + 1][w] & k[w] & ~r[w];
                r[w] |= a; g |= a;
            }
        }
        if (g) hfill8(r, k);                   // keep H-stable before vstab
        u64 tot = 0;
        if (__any((int)((g != 0ull) || redo))) {   // wave-uniform activity gate
            tot = vstab(r, k, lane, redo);
            if (lane == 0) {
#pragma unroll
                for (int w = 0; w < 8; ++w) Btop[wv][w] = r[w];
            }
            if (lane == 63) {
#pragma unroll
                for (int w = 0; w < 8; ++w) Bbot[wv][w] = r[w];
            }
        }
        if (!__syncthreads_or((int)(((g | tot) != 0ull) || redo))) break;
    }

    // word-interleaved output rout[ii*WPI + w*HW + row] (same format as k4 expects)
#pragma unroll
    for (int w = 0; w < 8; ++w)
        rout[(size_t)ii * WPI + (size_t)w * HW + t] = r[w];
}

// ---------------------------------------------------------------------------
// k4: fused output = OR of the two reconstructions (masked by cnt>0), f32 0/1.
// (unchanged — proven; rout word-interleaved idx = w*512 + row)
__global__ void k4_fuse(const u64* __restrict__ rout,
                        const u64* __restrict__ zm,
                        float* __restrict__ out) {
    size_t gid = (size_t)blockIdx.x * blockDim.x + threadIdx.x;
    size_t p = gid * 4;
    int n = (int)(p >> 18);
    int e = (int)(p & (NPIX - 1));
    size_t gw = (size_t)(((e >> 6) & 7) * HW + (e >> 9));
    u64 w = (rout[(size_t)n * WPI + gw] & zm[n])
          | (rout[(size_t)(16 + n) * WPI + gw] & zm[16 + n]);
    int sh = e & 63;
    float4 v;
    v.x = ((w >> sh) & 1ull)       ? 1.0f : 0.0f;
    v.y = ((w >> (sh + 1)) & 1ull) ? 1.0f : 0.0f;
    v.z = ((w >> (sh + 2)) & 1ull) ? 1.0f : 0.0f;
    v.w = ((w >> (sh + 3)) & 1ull) ? 1.0f : 0.0f;
    *(float4*)(out + 2 * (size_t)IN_ELEMS + p) = v;
}

extern "C" void kernel_launch(void* const* d_in, const int* in_sizes, int n_in,
                              void* d_out, int out_size, void* d_ws, size_t ws_size,
                              hipStream_t stream) {
    const float* A = (const float*)d_in[0];
    const float* B = (const float*)d_in[1];
    float* out = (float*)d_out;
    char* ws = (char*)d_ws;

    double* partA = (double*)(ws + WS_PARTA);
    u64*    zm    = (u64*)(ws + WS_ZM);
    u64*    msel  = (u64*)(ws + WS_MSEL);
    u64*    ksel  = (u64*)(ws + WS_KSEL);
    u64*    rout  = (u64*)(ws + WS_ROUT);

    k1_copy_stats<<<NII * CHUNKS, 256, 0, stream>>>(A, B, out, partA);
    k2_bits<<<NII * CHUNKS, 256, 0, stream>>>(A, B, partA, msel, ksel, zm);
    k3_flood<<<NII, 512, 0, stream>>>(msel, ksel, rout);
    k4_fuse<<<4096, 256, 0, stream>>>(rout, zm, out);
}

// Round 7
// 142.552 us; speedup vs baseline: 1.2712x; 1.2592x over previous
//
#include <hip/hip_runtime.h>
#include <cstdint>
#include <cstddef>

// Problem constants
#define HW 512
#define NPIX (HW * HW)           // 262144 pixels per image
#define NIMG 16
#define NII 32                   // (input j, image n) pairs: ii = j*16 + n
#define CHUNKS 64
#define CHUNK_PIX 4096
#define IN_ELEMS (NIMG * NPIX)   // 4194304 per input
#define WPI 4096                 // u64 words per ii (512 rows * 8)

typedef unsigned long long u64;

// Workspace layout (bytes)
#define WS_PARTA 0u                      // 32*64 entries * 4 doubles = 65536
#define WS_ZM    65536u                  // 32 u64
#define WS_MSEL  98304u                  // selected marker bitmaps (1 MB)
#define WS_KSEL  (WS_MSEL + 1048576u)    // selected mask bitmaps (1 MB)
#define WS_ROUT  (WS_KSEL + 1048576u)    // reconstruction result (1 MB)

// f64 sigmoid rounded to f32 — EXACT round-1 numerics. Used ONLY in find_cut.
__device__ __forceinline__ float sigmoid_f32(float x) {
    return (float)(1.0 / (1.0 + exp(-(double)x)));
}

// Fast f64 sigmoid for STATS ONLY (proven, absmax 0.0).
__device__ __forceinline__ float sigmoid_fast(float xf) {
    double x = (double)xf;
    double y = x * -1.4426950408889634074;     // log2(e)
    if (y > 1000.0)  return 0.0f;
    if (y < -1000.0) return 1.0f;
    double n = __builtin_rint(y);
    double t = (y - n) * 0.69314718055994530942;
    double p = 2.5052108385441718775e-8;
    p = __builtin_fma(p, t, 2.7557319223985890653e-7);
    p = __builtin_fma(p, t, 2.7557319223985892511e-6);
    p = __builtin_fma(p, t, 2.4801587301587301566e-5);
    p = __builtin_fma(p, t, 1.9841269841269841253e-4);
    p = __builtin_fma(p, t, 1.3888888888888889419e-3);
    p = __builtin_fma(p, t, 8.3333333333333332177e-3);
    p = __builtin_fma(p, t, 4.1666666666666664354e-2);
    p = __builtin_fma(p, t, 1.6666666666666665741e-1);
    p = __builtin_fma(p, t, 5.0e-1);
    p = __builtin_fma(p, t, 1.0);
    p = __builtin_fma(p, t, 1.0);
    long long bits = ((long long)n + 1023ll) << 52;
    double e = p * __longlong_as_double(bits);     // exp(-x)
    double d = 1.0 + e;
    if (y > 100.0 || y < -100.0)
        return (float)(1.0 / d);
    double r = (double)__builtin_amdgcn_rcpf((float)d);
    r = r * (2.0 - d * r);
    r = r * (2.0 - d * r);
    return (float)r;
}

// ---------------------------------------------------------------------------
// k1: single input pass — passthrough copy + f64 partials {sum,sumsq,cnt,max}.
// (byte-identical to the best-measured R0 configuration)
__global__ void k1_copy_stats(const float* __restrict__ A, const float* __restrict__ B,
                              float* __restrict__ out, double* __restrict__ partA) {
    int b = blockIdx.x;            // 0..2047
    int ii = b >> 6, chunk = b & 63;
    int j = ii >> 4, n = ii & 15;
    const float* src = (j == 0 ? A : B) + (size_t)n * NPIX + (size_t)chunk * CHUNK_PIX;
    float* dst = out + (size_t)j * IN_ELEMS + (size_t)n * NPIX + (size_t)chunk * CHUNK_PIX;

    double s = 0.0, sq = 0.0, cc = 0.0;
    float mx = -__builtin_inff();
#pragma unroll
    for (int p = 0; p < 4; ++p) {
        float4 v = *(const float4*)(src + p * 1024 + threadIdx.x * 4);
        *(float4*)(dst + p * 1024 + threadIdx.x * 4) = v;
        float xs[4] = {v.x, v.y, v.z, v.w};
#pragma unroll
        for (int q = 0; q < 4; ++q) {
            float img = sigmoid_fast(xs[q]);
            mx = fmaxf(mx, xs[q]);
            if (img > 0.0f) { double d = (double)img; s += d; sq += d * d; cc += 1.0; }
        }
    }
    __shared__ double sm[256], sv[256], sc[256];
    __shared__ float smx[256];
    sm[threadIdx.x] = s; sv[threadIdx.x] = sq; sc[threadIdx.x] = cc; smx[threadIdx.x] = mx;
    __syncthreads();
    for (int off = 128; off > 0; off >>= 1) {
        if (threadIdx.x < off) {
            sm[threadIdx.x] += sm[threadIdx.x + off];
            sv[threadIdx.x] += sv[threadIdx.x + off];
            sc[threadIdx.x] += sc[threadIdx.x + off];
            smx[threadIdx.x] = fmaxf(smx[threadIdx.x], smx[threadIdx.x + off]);
        }
        __syncthreads();
    }
    if (threadIdx.x == 0) {
        double* p = partA + (size_t)(ii * 64 + chunk) * 4;
        p[0] = sm[0]; p[1] = sv[0]; p[2] = sc[0]; p[3] = (double)smx[0];
    }
}

// ---------------------------------------------------------------------------
// cutoff bisection over ordered-f32 key space with the exact libm sigmoid
// (proven bit-exact).
__device__ __forceinline__ float key_to_f32(unsigned k) {
    unsigned b = (k & 0x80000000u) ? (k ^ 0x80000000u) : ~k;
    return __uint_as_float(b);
}
__device__ float find_cut(double T) {
    if (!(1.0 > T)) return __uint_as_float(0x7F800000u);
    unsigned lo = 0x007FFFFFu;   // key(-inf)
    unsigned hi = 0xFF800000u;   // key(+inf)
    while (lo < hi) {
        unsigned mid = lo + ((hi - lo) >> 1);
        float x = key_to_f32(mid);
        float s32 = sigmoid_f32(x);
        if ((double)s32 > T) hi = mid; else lo = mid + 1;
    }
    return key_to_f32(lo);
}

// ---------------------------------------------------------------------------
// k2: per-block redundant cutoff computation + selected marker/mask bitmaps
// via ballots + zm. (unchanged — proven)
__global__ void k2_bits(const float* __restrict__ A, const float* __restrict__ B,
                        const double* __restrict__ partA,
                        u64* __restrict__ msel, u64* __restrict__ ksel,
                        u64* __restrict__ zm) {
    int b = blockIdx.x, ii = b >> 6, chunk = b & 63;
    int j = ii >> 4, n = ii & 15;
    const float* src = (j == 0 ? A : B) + (size_t)n * NPIX;
    int t = threadIdx.x, lane = t & 63, w = t >> 6;

    __shared__ double shst[4];     // mean, sd, cnt, max
    __shared__ float cs[4];
    __shared__ float cut2[2];

    if (t < 64) {
        const double* p = partA + (size_t)(ii * 64 + t) * 4;
        double s = p[0], sq = p[1], c = p[2], mx = p[3];
#pragma unroll
        for (int off = 32; off > 0; off >>= 1) {
            s  += __shfl_down(s,  (unsigned)off, 64);
            sq += __shfl_down(sq, (unsigned)off, 64);
            c  += __shfl_down(c,  (unsigned)off, 64);
            mx  = fmax(mx, __shfl_down(mx, (unsigned)off, 64));
        }
        if (t == 0) {
            double mean = 0.0, sd = 0.0;
            if (c > 0.0) {
                mean = s / c;
                double var = sq / c - mean * mean;
                if (var < 0.0) var = 0.0;
                sd = sqrt(var);
            }
            shst[0] = mean; shst[1] = sd; shst[2] = c; shst[3] = mx;
        }
    }
    __syncthreads();
    if (t < 4) {
        double mean = shst[0], sd = shst[1];
        double fac = (ii < 16) ? 2.0 : 4.0;
        double T = (t == 0) ? mean + fac * sd
                 : (t == 1) ? mean + 0.5 * fac * sd
                 : (t == 2) ? mean + 0.5 * sd
                 :            mean + 0.25 * sd;
        cs[t] = find_cut(T);
    }
    __syncthreads();
    if (t == 0) {
        float mxf = (float)shst[3];
        cut2[0] = (mxf >= cs[0]) ? cs[0] : cs[1];   // marker (empty-fallback via max)
        cut2[1] = (mxf >= cs[2]) ? cs[2] : cs[3];   // mask
        if (chunk == 0) zm[ii] = (shst[2] > 0.0) ? ~0ull : 0ull;
    }
    __syncthreads();
    float cM = cut2[0], cK = cut2[1];

#pragma unroll 4
    for (int i = 0; i < 16; ++i) {
        float x = src[chunk * CHUNK_PIX + i * 256 + t];
        u64 bM = __ballot(x >= cM);
        u64 bK = __ballot(x >= cK);
        if (lane == 0) {
            size_t g = (size_t)ii * WPI + (size_t)chunk * 64 + i * 4 + w;
            msel[g] = bM; ksel[g] = bK;
        }
    }
}

// ---------------------------------------------------------------------------
// Masked horizontal fill of a 512-bit line to FIXPOINT in O(1) (proven).
__device__ __forceinline__ void hfill8(u64* x, const u64* k) {
    u64 c = 0;
#pragma unroll
    for (int w = 0; w < 8; ++w) {
        u64 a = k[w], g = x[w];
        u64 t1 = a + g;  u64 c1 = (u64)(t1 < a);
        u64 t2 = t1 + c; u64 c2 = (u64)(t2 < t1);
        c = c1 | c2;
        x[w] = (~t2 | g) & a;
    }
    c = 0;
#pragma unroll
    for (int w = 7; w >= 0; --w) {
        u64 a = __brevll(k[w]), g = __brevll(x[w]);
        u64 t1 = a + g;  u64 c1 = (u64)(t1 < a);
        u64 t2 = t1 + c; u64 c2 = (u64)(t2 < t1);
        c = c1 | c2;
        x[w] = __brevll((~t2 | g) & a);
    }
}

// ---------------------------------------------------------------------------
// k3: morphological reconstruction — free-running async Gauss-Seidel.
// PROVEN R0 structure (the only k3 that survived five redesign attempts:
// banding +9.5µs, pair-fusion 50µs, 4-row chains ~33µs, H/V transpose 64.7µs,
// register stripes 87.7µs — shfl is ds_permute, same LDS hardware). 32 blocks
// x 512 threads; thread t owns row t (registers), image mirrored in LDS
// (word-interleaved R[w*512+row], conflict-free). Sweeps run WITHOUT barriers:
// neighbor reads race with neighbor writes, which is monotone-safe (bits only
// turn on; a torn b64 read is old ⊆ value ⊆ fixpoint, and anything absorbed
// is masked by k so stays ⊆ fixpoint). Rows that gain bits re-run the O(1)
// horizontal fixpoint (hfill8) and write back. Every SWEEPS_PER_ROUND sweeps,
// one __syncthreads_or: exit only after a barrier-delimited window in which
// NO thread gained -> state is the true fixpoint (monotone + stable).
// R7 tweak: window 4 -> 6 sweeps (fewer barrier/report rounds for the same
// total sweep count; post-fixpoint sweeps are cheap: diff=0 -> no hfill, no
// writes). Certification logic is window-length independent.
#define SWEEPS_PER_ROUND 6
__global__ __launch_bounds__(512) void k3_flood(const u64* __restrict__ msel,
                                                const u64* __restrict__ ksel,
                                                u64* __restrict__ rout) {
    int ii = blockIdx.x, t = threadIdx.x;   // t = row index
    __shared__ u64 R[8 * HW];               // 32 KB
    const u64* M = msel + (size_t)ii * WPI;
    const u64* K = ksel + (size_t)ii * WPI;

    u64 r[8], k[8];
#pragma unroll
    for (int w = 0; w < 8; ++w) {
        k[w] = K[(size_t)t * 8 + w];
        r[w] = M[(size_t)t * 8 + w] & k[w];   // marker ⊆ mask (Tm >= Tk always)
    }
    hfill8(r, k);                              // initial horizontal fixpoint
#pragma unroll
    for (int w = 0; w < 8; ++w) R[w * HW + t] = r[w];
    __syncthreads();

    for (int round = 0; round < 200; ++round) {   // 1200 sweeps max >> worst case
        u64 gained = 0;
#pragma unroll 1
        for (int sweep = 0; sweep < SWEEPS_PER_ROUND; ++sweep) {
            u64 diff = 0;
#pragma unroll
            for (int w = 0; w < 8; ++w) {
                u64 nb = (t > 0      ? R[w * HW + (t - 1)] : 0ull)
                       | (t < HW - 1 ? R[w * HW + (t + 1)] : 0ull);
                u64 g = nb & k[w] & ~r[w];
                r[w] |= g; diff |= g;
            }
            if (diff) {        // uniform-false waves skip (s_cbranch_execz)
                hfill8(r, k);
#pragma unroll
                for (int w = 0; w < 8; ++w) R[w * HW + t] = r[w];
                gained |= diff;
            }
            asm volatile("" ::: "memory");   // force LDS re-read next sweep
        }
        if (!__syncthreads_or(gained != 0ull ? 1 : 0)) break;
    }

    // word-interleaved output: per w, 64 lanes store 512 contiguous bytes
#pragma unroll
    for (int w = 0; w < 8; ++w)
        rout[(size_t)ii * WPI + (size_t)w * HW + t] = r[w];
}

// ---------------------------------------------------------------------------
// k4: fused output = OR of the two reconstructions (masked by cnt>0), f32 0/1.
// (unchanged — proven; rout word-interleaved idx = w*512 + row)
__global__ void k4_fuse(const u64* __restrict__ rout,
                        const u64* __restrict__ zm,
                        float* __restrict__ out) {
    size_t gid = (size_t)blockIdx.x * blockDim.x + threadIdx.x;
    size_t p = gid * 4;
    int n = (int)(p >> 18);
    int e = (int)(p & (NPIX - 1));
    size_t gw = (size_t)(((e >> 6) & 7) * HW + (e >> 9));
    u64 w = (rout[(size_t)n * WPI + gw] & zm[n])
          | (rout[(size_t)(16 + n) * WPI + gw] & zm[16 + n]);
    int sh = e & 63;
    float4 v;
    v.x = ((w >> sh) & 1ull)       ? 1.0f : 0.0f;
    v.y = ((w >> (sh + 1)) & 1ull) ? 1.0f : 0.0f;
    v.z = ((w >> (sh + 2)) & 1ull) ? 1.0f : 0.0f;
    v.w = ((w >> (sh + 3)) & 1ull) ? 1.0f : 0.0f;
    *(float4*)(out + 2 * (size_t)IN_ELEMS + p) = v;
}

extern "C" void kernel_launch(void* const* d_in, const int* in_sizes, int n_in,
                              void* d_out, int out_size, void* d_ws, size_t ws_size,
                              hipStream_t stream) {
    const float* A = (const float*)d_in[0];
    const float* B = (const float*)d_in[1];
    float* out = (float*)d_out;
    char* ws = (char*)d_ws;

    double* partA = (double*)(ws + WS_PARTA);
    u64*    zm    = (u64*)(ws + WS_ZM);
    u64*    msel  = (u64*)(ws + WS_MSEL);
    u64*    ksel  = (u64*)(ws + WS_KSEL);
    u64*    rout  = (u64*)(ws + WS_ROUT);

    k1_copy_stats<<<NII * CHUNKS, 256, 0, stream>>>(A, B, out, partA);
    k2_bits<<<NII * CHUNKS, 256, 0, stream>>>(A, B, partA, msel, ksel, zm);
    k3_flood<<<NII, 512, 0, stream>>>(msel, ksel, rout);
    k4_fuse<<<4096, 256, 0, stream>>>(rout, zm, out);
}